// Round 6
// baseline (276.526 us; speedup 1.0000x reference)
//
#include <hip/hip_runtime.h>

typedef __bf16 bf16;
typedef __bf16 bf16x4 __attribute__((ext_vector_type(4)));
typedef __bf16 bf16x8 __attribute__((ext_vector_type(8)));
typedef float  floatx4 __attribute__((ext_vector_type(4)));

#define MFMA16(a,b,c) __builtin_amdgcn_mfma_f32_16x16x32_bf16((a),(b),(c),0,0,0)

static constexpr int S_LEN = 4096;
static constexpr int DM = 768;
static constexpr int NH = 12;
static constexpr int W_ELEMS = 768 * 768;
static constexpr int PARTS_PER_HEAD = 144;  // sum over qb=0..31 of ceil((qb+1)/4)
static constexpr float CE = 0.18033688011112042f;  // log2(e)/sqrt(64), folded into Q proj

__device__ __forceinline__ void gld16(const bf16* g, bf16* l) {
    __builtin_amdgcn_global_load_lds(
        (const __attribute__((address_space(1))) void*)g,
        (__attribute__((address_space(3))) void*)l, 16, 0, 0);
}

// ---------------------------------------------------------------------------
// prep: y<3 -> cast q/k/v fp32->bf16; y==3 -> cast+transpose 4 weight mats
// ---------------------------------------------------------------------------
__global__ __launch_bounds__(256) void prep_kernel(
    const float* __restrict__ q, const float* __restrict__ k, const float* __restrict__ v,
    const float* __restrict__ W0, const float* __restrict__ W1,
    const float* __restrict__ W2, const float* __restrict__ W3,
    bf16* Qc, bf16* Kc, bf16* Vc,
    bf16* T0, bf16* T1, bf16* T2, bf16* T3, int n)
{
    const int y = blockIdx.y;
    const int tid = threadIdx.x;
    if (y < 3) {
        const float* src = y == 0 ? q : (y == 1 ? k : v);
        bf16* dst = y == 0 ? Qc : (y == 1 ? Kc : Vc);
        int i = (blockIdx.x * 256 + tid) * 4;
        if (i < n) {
            float4 w = *(const float4*)&src[i];
            bf16x4 o; o[0] = (bf16)w.x; o[1] = (bf16)w.y; o[2] = (bf16)w.z; o[3] = (bf16)w.w;
            *(bf16x4*)&dst[i] = o;
        }
        return;
    }
    int x = blockIdx.x;
    if (x >= 576) return;
    const int mat = x / 144, t = x % 144;
    const float* W = mat == 0 ? W0 : (mat == 1 ? W1 : (mat == 2 ? W2 : W3));
    bf16* T = mat == 0 ? T0 : (mat == 1 ? T1 : (mat == 2 ? T2 : T3));
    const int k0 = (t / 12) * 64, n0 = (t % 12) * 64;
    __shared__ float Tl[64][65];
#pragma unroll
    for (int i = 0; i < 4; ++i) {
        int idx = i * 256 + tid;
        int r = idx >> 4, c4 = idx & 15;
        float4 w = *(const float4*)&W[(k0 + r) * 768 + n0 + c4 * 4];
        Tl[c4 * 4 + 0][r] = w.x; Tl[c4 * 4 + 1][r] = w.y;
        Tl[c4 * 4 + 2][r] = w.z; Tl[c4 * 4 + 3][r] = w.w;
    }
    __syncthreads();
#pragma unroll
    for (int i = 0; i < 4; ++i) {
        int idx = i * 256 + tid;
        int c = idx >> 4, r4 = idx & 15;
        bf16x4 o;
        o[0] = (bf16)Tl[c][r4 * 4 + 0]; o[1] = (bf16)Tl[c][r4 * 4 + 1];
        o[2] = (bf16)Tl[c][r4 * 4 + 2]; o[3] = (bf16)Tl[c][r4 * 4 + 3];
        *(bf16x4*)&T[(n0 + c) * 768 + k0 + r4 * 4] = o;
    }
}

// ---------------------------------------------------------------------------
// GEMM: C[M,N] = (A[M,K] @ Bt[N,K]^T + bias) * scale(z). 128x128, BK=64,
// pipelined dbuf + gld_lds(16B), addr-side XOR swizzle. (frozen since R5)
// ---------------------------------------------------------------------------
template <bool OUT_F32>
__global__ __launch_bounds__(256) void gemm128_kernel(
    const bf16* __restrict__ A0, const bf16* __restrict__ A1, const bf16* __restrict__ A2,
    const bf16* __restrict__ B0, const bf16* __restrict__ B1, const bf16* __restrict__ B2,
    const float* __restrict__ c0, const float* __restrict__ c1, const float* __restrict__ c2,
    void* O0, void* O1, void* O2, int M, int N, int K, float qscale)
{
    const int z = blockIdx.z;
    const bf16* A = z == 0 ? A0 : (z == 1 ? A1 : A2);
    const bf16* B = z == 0 ? B0 : (z == 1 ? B1 : B2);
    const float* bias = z == 0 ? c0 : (z == 1 ? c1 : c2);
    void* C = z == 0 ? O0 : (z == 1 ? O1 : O2);
    const float osc = (z == 0) ? qscale : 1.0f;

    __shared__ bf16 As[2][128 * 64];
    __shared__ bf16 Bs[2][128 * 64];
    const int tid = threadIdx.x, lane = tid & 63, wave = tid >> 6;
    const int quad = lane >> 4, l16 = lane & 15, l8 = l16 & 7;
    const int rw = wave >> 1, cw = wave & 1;
    const int m0 = blockIdx.x * 128, n0 = blockIdx.y * 128;

    floatx4 acc[4][4] = {};

    auto stage = [&](int kt, int buf) {
#pragma unroll
        for (int i = 0; i < 4; ++i) {
            int ch = i * 256 + tid;
            int m = ch >> 3, kg = ch & 7;
            int kgd = kg ^ (m & 7);
            gld16(A + (size_t)(m0 + m) * K + kt * 64 + kgd * 8, &As[buf][ch * 8]);
        }
#pragma unroll
        for (int i = 0; i < 4; ++i) {
            int ch = i * 256 + tid;
            int n = ch >> 3, kg = ch & 7;
            int kgd = kg ^ (n & 7);
            gld16(B + (size_t)(n0 + n) * K + kt * 64 + kgd * 8, &Bs[buf][ch * 8]);
        }
    };

    const int NT = K >> 6;
    stage(0, 0);
    __syncthreads();

    for (int kt = 0; kt < NT; ++kt) {
        const int cur = kt & 1;
        if (kt + 1 < NT) stage(kt + 1, cur ^ 1);
#pragma unroll
        for (int ks = 0; ks < 2; ++ks) {
            bf16x8 a[4], b[4];
#pragma unroll
            for (int mt = 0; mt < 4; ++mt)
                a[mt] = *(const bf16x8*)&As[cur][(rw * 64 + mt * 16 + l16) * 64 + (((ks * 4 + quad) ^ l8) << 3)];
#pragma unroll
            for (int nt = 0; nt < 4; ++nt)
                b[nt] = *(const bf16x8*)&Bs[cur][(cw * 64 + nt * 16 + l16) * 64 + (((ks * 4 + quad) ^ l8) << 3)];
#pragma unroll
            for (int mt = 0; mt < 4; ++mt)
#pragma unroll
                for (int nt = 0; nt < 4; ++nt)
                    acc[mt][nt] = MFMA16(a[mt], b[nt], acc[mt][nt]);
        }
        __syncthreads();
    }
#pragma unroll
    for (int mt = 0; mt < 4; ++mt) {
        int row = m0 + rw * 64 + mt * 16 + quad * 4;
#pragma unroll
        for (int nt = 0; nt < 4; ++nt) {
            int col = n0 + cw * 64 + nt * 16 + l16;
            float bv = bias[col];
#pragma unroll
            for (int r = 0; r < 4; ++r) {
                float v = (acc[mt][nt][r] + bv) * osc;
                if (OUT_F32) ((float*)C)[(size_t)(row + r) * N + col] = v;
                else         ((bf16*)C)[(size_t)(row + r) * N + col] = (bf16)v;
            }
        }
    }
}

// ---------------------------------------------------------------------------
// Split-K causal flash attention, S^T formulation, UNIFORM chunks of 8 tiles.
// Per qb (128 q-rows): ntiles = 2qb+2, nc = ceil((qb+1)/4) chunks. All heavy
// chunks are exactly 8 iters -> per-CU load balances regardless of dispatch.
// idx->(qb,c): group g = qb>>2 has 4 qbs x (g+1) chunks, base(g) = 2g(g+1).
// ---------------------------------------------------------------------------
__global__ __launch_bounds__(256) void attn_kernel(
    const bf16* __restrict__ Q, const bf16* __restrict__ K,
    const bf16* __restrict__ V, float* __restrict__ Opart,
    float* __restrict__ Lpart)
{
    __shared__ bf16 Ps[128 * 64];    // [q][key] wave-private rows, chunk-swizzled
    __shared__ bf16 Ks[2][64 * 64];  // [key][d] gld_lds dbuf, addr-swizzled
    __shared__ bf16 Vt[64 * 64];     // [d][key] single buffer, reg-gather transpose

    const int h = blockIdx.y;
    const int idx = PARTS_PER_HEAD - 1 - (int)blockIdx.x;   // heavy chunks first
    int g = 0;
    while (2 * (g + 1) * (g + 2) <= idx) ++g;               // <=7 iters, uniform
    const int rem = idx - 2 * g * (g + 1);
    const int qb = 4 * g + rem / (g + 1);
    const int c  = rem % (g + 1);
    const int ntiles = 2 * qb + 2;
    const int jstart = c * 8;
    const int jend   = (jstart + 8 < ntiles) ? jstart + 8 : ntiles;  // exclusive

    const int tid = threadIdx.x, lane = tid & 63, wave = tid >> 6;
    const int quad = lane >> 4, l16 = lane & 15, l8 = l16 & 7;
    const int qrow0 = qb * 128;
    const int cb = h * 64;

    auto stageK = [&](int j, int buf) {
#pragma unroll
        for (int i = 0; i < 2; ++i) {
            int ch = i * 256 + tid;
            int row = ch >> 3, kg = ch & 7;
            int kgd = kg ^ (row & 7);
            gld16(K + (size_t)(j * 64 + row) * DM + cb + kgd * 8, &Ks[buf][ch * 8]);
        }
    };
    auto loadV = [&](int j, bf16 vr[2][8]) {
#pragma unroll
        for (int i = 0; i < 2; ++i) {
            int kg = wave + i * 4;
#pragma unroll
            for (int u = 0; u < 8; ++u)
                vr[i][u] = V[(size_t)(j * 64 + kg * 8 + u) * DM + cb + lane];
        }
    };
    auto writeV = [&](bf16 vr[2][8]) {
#pragma unroll
        for (int i = 0; i < 2; ++i) {
            int kg = wave + i * 4;
            bf16x8 t;
#pragma unroll
            for (int u = 0; u < 8; ++u) t[u] = vr[i][u];
            *(bf16x8*)&Vt[lane * 64 + ((kg ^ (lane & 7)) << 3)] = t;
        }
    };

    // Q fragments (A-layout == B-layout of Q^T element-wise): wave-private rows
    bf16x8 qreg[2][2];
#pragma unroll
    for (int mt = 0; mt < 2; ++mt)
#pragma unroll
        for (int ks = 0; ks < 2; ++ks)
            qreg[mt][ks] = *(const bf16x8*)&Q[(size_t)(qrow0 + wave * 32 + mt * 16 + l16) * DM
                                             + cb + ks * 32 + quad * 8];

    // prologue
    stageK(jstart, 0);
    bf16 v0[2][8];
    loadV(jstart, v0);
    writeV(v0);
    __syncthreads();

    floatx4 o[2][4] = {};
    float lsum[2] = {0.f, 0.f};
    const int prowbase = (wave * 32 + l16) * 64;           // + mt*16*64
    const int psub = (quad & 1) * 4;
    const int c16base = (quad >> 1);

    for (int j = jstart; j < jend; ++j) {
        const int cur = (j - jstart) & 1;
        bf16 vr[2][8];
        if (j + 1 < jend) {
            stageK(j + 1, cur ^ 1);
            loadV(j + 1, vr);
        }

        // S^T = K @ Q^T   (lane: k = ct*16 + quad*4 + r, q = subtile + l16)
        floatx4 st[2][4] = {};
#pragma unroll
        for (int ks = 0; ks < 2; ++ks) {
            bf16x8 kfr[4];
#pragma unroll
            for (int ct = 0; ct < 4; ++ct)
                kfr[ct] = *(const bf16x8*)&Ks[cur][(ct * 16 + l16) * 64 + (((ks * 4 + quad) ^ l8) << 3)];
#pragma unroll
            for (int mt = 0; mt < 2; ++mt)
#pragma unroll
                for (int ct = 0; ct < 4; ++ct)
                    st[mt][ct] = MFMA16(kfr[ct], qreg[mt][ks], st[mt][ct]);
        }

        // softmax: p = exp2(st) (Q prescaled); pack 4 consecutive-k -> b64
#pragma unroll
        for (int mt = 0; mt < 2; ++mt) {
            const int qs0 = qrow0 + wave * 32 + mt * 16;
            const int pb = prowbase + mt * 16 * 64;
            float lp = 0.f;
            if ((j * 64 + 63) <= qs0) {          // interior tile: no mask ops
#pragma unroll
                for (int ct = 0; ct < 4; ++ct) {
                    bf16x4 pk;
#pragma unroll
                    for (int r = 0; r < 4; ++r) {
                        float p = __builtin_amdgcn_exp2f(st[mt][ct][r]);
                        lp += p; pk[r] = (bf16)p;
                    }
                    *(bf16x4*)&Ps[pb + ((((ct * 2 + c16base) ^ l8) << 3) + psub)] = pk;
                }
            } else {                              // diagonal tile: mask k > q
                const int qg = qs0 + l16;
#pragma unroll
                for (int ct = 0; ct < 4; ++ct) {
                    const int kg0 = j * 64 + ct * 16 + quad * 4;
                    bf16x4 pk;
#pragma unroll
                    for (int r = 0; r < 4; ++r) {
                        float p = (kg0 + r > qg) ? 0.f
                                  : __builtin_amdgcn_exp2f(st[mt][ct][r]);
                        lp += p; pk[r] = (bf16)p;
                    }
                    *(bf16x4*)&Ps[pb + ((((ct * 2 + c16base) ^ l8) << 3) + psub)] = pk;
                }
            }
            lsum[mt] += lp;
        }
        // Ps rows wave-private: no barrier

        // O += P @ V   (A = Ps b128 swizzled, B = Vt)
#pragma unroll
        for (int ks = 0; ks < 2; ++ks) {
            bf16x8 bfr[4], afr[2];
#pragma unroll
            for (int ct = 0; ct < 4; ++ct)
                bfr[ct] = *(const bf16x8*)&Vt[(ct * 16 + l16) * 64 + (((ks * 4 + quad) ^ l8) << 3)];
#pragma unroll
            for (int mt = 0; mt < 2; ++mt)
                afr[mt] = *(const bf16x8*)&Ps[(wave * 32 + mt * 16 + l16) * 64 + (((ks * 4 + quad) ^ l8) << 3)];
#pragma unroll
            for (int mt = 0; mt < 2; ++mt)
#pragma unroll
                for (int ct = 0; ct < 4; ++ct)
                    o[mt][ct] = MFMA16(afr[mt], bfr[ct], o[mt][ct]);
        }

        if (j + 1 < jend) {
            __syncthreads();   // all waves done with Vt/Ks[cur]; drains prefetch vmcnt
            writeV(vr);
            __syncthreads();   // Vt(j+1) visible
        }
    }

    // epilogue: write unnormalized fp32 partial + per-row l
    float* Op = Opart + (size_t)(h * PARTS_PER_HEAD + idx) * 128 * 64;
    float* Lp = Lpart + (size_t)(h * PARTS_PER_HEAD + idx) * 128;
#pragma unroll
    for (int mt = 0; mt < 2; ++mt) {
        float l = lsum[mt];
        l += __shfl_xor(l, 16);
        l += __shfl_xor(l, 32);                  // full l for q = subtile + l16
        if (lane < 16) Lp[wave * 32 + mt * 16 + l16] = l;
#pragma unroll
        for (int r = 0; r < 4; ++r) {
            const int rl = wave * 32 + mt * 16 + quad * 4 + r;
#pragma unroll
            for (int ct = 0; ct < 4; ++ct)
                Op[rl * 64 + ct * 16 + l16] = o[mt][ct][r];
        }
    }
}

// ---------------------------------------------------------------------------
// combine: X = (sum of partial O) / (sum of partial l), bf16
// ---------------------------------------------------------------------------
__global__ __launch_bounds__(256) void attn_combine_kernel(
    const float* __restrict__ Opart, const float* __restrict__ Lpart,
    bf16* __restrict__ X)
{
    const int qb = blockIdx.x, h = blockIdx.y;
    const int g = qb >> 2;
    const int nc = g + 1;
    const int base = 2 * g * (g + 1) + (qb & 3) * (g + 1);
    const float* Op0 = Opart + (size_t)(h * PARTS_PER_HEAD + base) * 128 * 64;
    const float* Lp0 = Lpart + (size_t)(h * PARTS_PER_HEAD + base) * 128;

    for (int e = threadIdx.x * 4; e < 128 * 64; e += 1024) {
        const int row = e >> 6, col = e & 63;
        float4 acc = {0.f, 0.f, 0.f, 0.f};
        float l = 0.f;
        for (int p = 0; p < nc; ++p) {
            float4 w = *(const float4*)&Op0[p * 128 * 64 + e];
            acc.x += w.x; acc.y += w.y; acc.z += w.z; acc.w += w.w;
            l += Lp0[p * 128 + row];
        }
        const float rl = 1.0f / l;
        bf16x4 ov;
        ov[0] = (bf16)(acc.x * rl); ov[1] = (bf16)(acc.y * rl);
        ov[2] = (bf16)(acc.z * rl); ov[3] = (bf16)(acc.w * rl);
        *(bf16x4*)&X[(size_t)(qb * 128 + row) * DM + h * 64 + col] = ov;
    }
}

// ---------------------------------------------------------------------------
extern "C" void kernel_launch(void* const* d_in, const int* in_sizes, int n_in,
                              void* d_out, int out_size, void* d_ws, size_t ws_size,
                              hipStream_t stream)
{
    const float* q  = (const float*)d_in[0];
    const float* k  = (const float*)d_in[1];
    const float* v  = (const float*)d_in[2];
    // d_in[3] = causal mask, handled analytically
    const float* Wq = (const float*)d_in[4];
    const float* bq = (const float*)d_in[5];
    const float* Wk = (const float*)d_in[6];
    const float* bk = (const float*)d_in[7];
    const float* Wv = (const float*)d_in[8];
    const float* bv = (const float*)d_in[9];
    const float* Wo = (const float*)d_in[10];
    const float* bo = (const float*)d_in[11];

    const size_t NE = (size_t)S_LEN * DM;     // 3,145,728 elems
    bf16* base = (bf16*)d_ws;
    // persistent through attn:
    bf16* Qp = base;                          // also reused as Xb after attn
    bf16* Kp = base + NE;
    bf16* Vp = base + 2 * NE;
    bf16* Wt = base + 3 * NE;                 // 4 transposed bf16 weights
    bf16 *Wqt = Wt, *Wkt = Wt + W_ELEMS, *Wvt = Wt + 2 * W_ELEMS, *Wot = Wt + 3 * W_ELEMS;
    // scratch region: Qc/Kc/Vc (prep->gemmQKV) OVERLAID by Opart/Lpart (attn->combine)
    bf16* scratch = Wt + 4 * W_ELEMS;
    bf16* Qc = scratch;
    bf16* Kc = scratch + NE;
    bf16* Vc = scratch + 2 * NE;
    float* Opart = (float*)scratch;           // 12*144*128*64 fp32 = 56.6 MB
    float* Lpart = Opart + (size_t)NH * PARTS_PER_HEAD * 128 * 64;
    bf16* Xb = Qp;                            // Qp dead after attn

    prep_kernel<<<dim3(3072, 4), 256, 0, stream>>>(
        q, k, v, Wq, Wk, Wv, Wo, Qc, Kc, Vc, Wqt, Wkt, Wvt, Wot, (int)NE);
    gemm128_kernel<false><<<dim3(32, 6, 3), 256, 0, stream>>>(
        Qc, Kc, Vc, Wqt, Wkt, Wvt, bq, bk, bv, Qp, Kp, Vp, S_LEN, DM, DM, CE);
    attn_kernel<<<dim3(PARTS_PER_HEAD, NH), 256, 0, stream>>>(Qp, Kp, Vp, Opart, Lpart);
    attn_combine_kernel<<<dim3(32, NH), 256, 0, stream>>>(Opart, Lpart, Xb);
    gemm128_kernel<true><<<dim3(32, 6, 1), 256, 0, stream>>>(
        Xb, Xb, Xb, Wot, Wot, Wot, bo, bo, bo, d_out, d_out, d_out, S_LEN, DM, DM, 1.0f);
}

// Round 7
// 260.580 us; speedup vs baseline: 1.0612x; 1.0612x over previous
//
#include <hip/hip_runtime.h>

typedef __bf16 bf16;
typedef __bf16 bf16x4 __attribute__((ext_vector_type(4)));
typedef __bf16 bf16x8 __attribute__((ext_vector_type(8)));
typedef float  floatx4 __attribute__((ext_vector_type(4)));

#define MFMA16(a,b,c) __builtin_amdgcn_mfma_f32_16x16x32_bf16((a),(b),(c),0,0,0)

static constexpr int S_LEN = 4096;
static constexpr int DM = 768;
static constexpr int NH = 12;
static constexpr int W_ELEMS = 768 * 768;
static constexpr int PARTS_PER_HEAD = 144;  // sum over qb=0..31 of ceil((qb+1)/4)
static constexpr float CE = 0.18033688011112042f;  // log2(e)/sqrt(64), folded into Q proj

__device__ __forceinline__ void gld16(const bf16* g, bf16* l) {
    __builtin_amdgcn_global_load_lds(
        (const __attribute__((address_space(1))) void*)g,
        (__attribute__((address_space(3))) void*)l, 16, 0, 0);
}

// ---------------------------------------------------------------------------
// prep: y<3 -> cast q/k/v fp32->bf16; y==3 -> cast+transpose 4 weight mats
// ---------------------------------------------------------------------------
__global__ __launch_bounds__(256) void prep_kernel(
    const float* __restrict__ q, const float* __restrict__ k, const float* __restrict__ v,
    const float* __restrict__ W0, const float* __restrict__ W1,
    const float* __restrict__ W2, const float* __restrict__ W3,
    bf16* Qc, bf16* Kc, bf16* Vc,
    bf16* T0, bf16* T1, bf16* T2, bf16* T3, int n)
{
    const int y = blockIdx.y;
    const int tid = threadIdx.x;
    if (y < 3) {
        const float* src = y == 0 ? q : (y == 1 ? k : v);
        bf16* dst = y == 0 ? Qc : (y == 1 ? Kc : Vc);
        int i = (blockIdx.x * 256 + tid) * 4;
        if (i < n) {
            float4 w = *(const float4*)&src[i];
            bf16x4 o; o[0] = (bf16)w.x; o[1] = (bf16)w.y; o[2] = (bf16)w.z; o[3] = (bf16)w.w;
            *(bf16x4*)&dst[i] = o;
        }
        return;
    }
    int x = blockIdx.x;
    if (x >= 576) return;
    const int mat = x / 144, t = x % 144;
    const float* W = mat == 0 ? W0 : (mat == 1 ? W1 : (mat == 2 ? W2 : W3));
    bf16* T = mat == 0 ? T0 : (mat == 1 ? T1 : (mat == 2 ? T2 : T3));
    const int k0 = (t / 12) * 64, n0 = (t % 12) * 64;
    __shared__ float Tl[64][65];
#pragma unroll
    for (int i = 0; i < 4; ++i) {
        int idx = i * 256 + tid;
        int r = idx >> 4, c4 = idx & 15;
        float4 w = *(const float4*)&W[(k0 + r) * 768 + n0 + c4 * 4];
        Tl[c4 * 4 + 0][r] = w.x; Tl[c4 * 4 + 1][r] = w.y;
        Tl[c4 * 4 + 2][r] = w.z; Tl[c4 * 4 + 3][r] = w.w;
    }
    __syncthreads();
#pragma unroll
    for (int i = 0; i < 4; ++i) {
        int idx = i * 256 + tid;
        int c = idx >> 4, r4 = idx & 15;
        bf16x4 o;
        o[0] = (bf16)Tl[c][r4 * 4 + 0]; o[1] = (bf16)Tl[c][r4 * 4 + 1];
        o[2] = (bf16)Tl[c][r4 * 4 + 2]; o[3] = (bf16)Tl[c][r4 * 4 + 3];
        *(bf16x4*)&T[(n0 + c) * 768 + k0 + r4 * 4] = o;
    }
}

// ---------------------------------------------------------------------------
// vtrans: VpT[768][4096] = Vp[4096][768]^T, 64x64 LDS tiles (bf16 in/out)
// ---------------------------------------------------------------------------
__global__ __launch_bounds__(256) void vtrans_kernel(
    const bf16* __restrict__ Vp, bf16* __restrict__ VpT)
{
    __shared__ bf16 Tl[64][66];   // +2 pad: conflict-light
    const int tid = threadIdx.x;
    const int r0 = blockIdx.x * 64, c0 = blockIdx.y * 64;
#pragma unroll
    for (int i = 0; i < 4; ++i) {
        int idx = i * 256 + tid;
        int r = idx >> 4, c4 = idx & 15;
        bf16x4 w = *(const bf16x4*)&Vp[(size_t)(r0 + r) * DM + c0 + c4 * 4];
        Tl[c4 * 4 + 0][r] = w[0]; Tl[c4 * 4 + 1][r] = w[1];
        Tl[c4 * 4 + 2][r] = w[2]; Tl[c4 * 4 + 3][r] = w[3];
    }
    __syncthreads();
#pragma unroll
    for (int i = 0; i < 4; ++i) {
        int idx = i * 256 + tid;
        int c = idx >> 4, r4 = idx & 15;
        bf16x4 o;
        o[0] = Tl[c][r4 * 4 + 0]; o[1] = Tl[c][r4 * 4 + 1];
        o[2] = Tl[c][r4 * 4 + 2]; o[3] = Tl[c][r4 * 4 + 3];
        *(bf16x4*)&VpT[(size_t)(c0 + c) * S_LEN + r0 + r4 * 4] = o;
    }
}

// ---------------------------------------------------------------------------
// GEMM: C[M,N] = (A[M,K] @ Bt[N,K]^T + bias) * scale(z). 128x128, BK=64,
// pipelined dbuf + gld_lds(16B), addr-side XOR swizzle. (frozen since R5)
// ---------------------------------------------------------------------------
template <bool OUT_F32>
__global__ __launch_bounds__(256) void gemm128_kernel(
    const bf16* __restrict__ A0, const bf16* __restrict__ A1, const bf16* __restrict__ A2,
    const bf16* __restrict__ B0, const bf16* __restrict__ B1, const bf16* __restrict__ B2,
    const float* __restrict__ c0, const float* __restrict__ c1, const float* __restrict__ c2,
    void* O0, void* O1, void* O2, int M, int N, int K, float qscale)
{
    const int z = blockIdx.z;
    const bf16* A = z == 0 ? A0 : (z == 1 ? A1 : A2);
    const bf16* B = z == 0 ? B0 : (z == 1 ? B1 : B2);
    const float* bias = z == 0 ? c0 : (z == 1 ? c1 : c2);
    void* C = z == 0 ? O0 : (z == 1 ? O1 : O2);
    const float osc = (z == 0) ? qscale : 1.0f;

    __shared__ bf16 As[2][128 * 64];
    __shared__ bf16 Bs[2][128 * 64];
    const int tid = threadIdx.x, lane = tid & 63, wave = tid >> 6;
    const int quad = lane >> 4, l16 = lane & 15, l8 = l16 & 7;
    const int rw = wave >> 1, cw = wave & 1;
    const int m0 = blockIdx.x * 128, n0 = blockIdx.y * 128;

    floatx4 acc[4][4] = {};

    auto stage = [&](int kt, int buf) {
#pragma unroll
        for (int i = 0; i < 4; ++i) {
            int ch = i * 256 + tid;
            int m = ch >> 3, kg = ch & 7;
            int kgd = kg ^ (m & 7);
            gld16(A + (size_t)(m0 + m) * K + kt * 64 + kgd * 8, &As[buf][ch * 8]);
        }
#pragma unroll
        for (int i = 0; i < 4; ++i) {
            int ch = i * 256 + tid;
            int n = ch >> 3, kg = ch & 7;
            int kgd = kg ^ (n & 7);
            gld16(B + (size_t)(n0 + n) * K + kt * 64 + kgd * 8, &Bs[buf][ch * 8]);
        }
    };

    const int NT = K >> 6;
    stage(0, 0);
    __syncthreads();

    for (int kt = 0; kt < NT; ++kt) {
        const int cur = kt & 1;
        if (kt + 1 < NT) stage(kt + 1, cur ^ 1);
#pragma unroll
        for (int ks = 0; ks < 2; ++ks) {
            bf16x8 a[4], b[4];
#pragma unroll
            for (int mt = 0; mt < 4; ++mt)
                a[mt] = *(const bf16x8*)&As[cur][(rw * 64 + mt * 16 + l16) * 64 + (((ks * 4 + quad) ^ l8) << 3)];
#pragma unroll
            for (int nt = 0; nt < 4; ++nt)
                b[nt] = *(const bf16x8*)&Bs[cur][(cw * 64 + nt * 16 + l16) * 64 + (((ks * 4 + quad) ^ l8) << 3)];
#pragma unroll
            for (int mt = 0; mt < 4; ++mt)
#pragma unroll
                for (int nt = 0; nt < 4; ++nt)
                    acc[mt][nt] = MFMA16(a[mt], b[nt], acc[mt][nt]);
        }
        __syncthreads();
    }
#pragma unroll
    for (int mt = 0; mt < 4; ++mt) {
        int row = m0 + rw * 64 + mt * 16 + quad * 4;
#pragma unroll
        for (int nt = 0; nt < 4; ++nt) {
            int col = n0 + cw * 64 + nt * 16 + l16;
            float bv = bias[col];
#pragma unroll
            for (int r = 0; r < 4; ++r) {
                float v = (acc[mt][nt][r] + bv) * osc;
                if (OUT_F32) ((float*)C)[(size_t)(row + r) * N + col] = v;
                else         ((bf16*)C)[(size_t)(row + r) * N + col] = (bf16)v;
            }
        }
    }
}

// ---------------------------------------------------------------------------
// Split-K causal flash attention, S^T formulation, uniform chunks of 8 tiles.
// K AND V^T both staged via async gld_lds double-buffer (V pre-transposed by
// vtrans) -> zero per-iter scalar loads, ONE barrier per iteration.
// bf16 partials (halved combine traffic).
// ---------------------------------------------------------------------------
__global__ __launch_bounds__(256) void attn_kernel(
    const bf16* __restrict__ Q, const bf16* __restrict__ K,
    const bf16* __restrict__ VpT, bf16* __restrict__ Opart,
    float* __restrict__ Lpart)
{
    __shared__ bf16 Ps[128 * 64];    // [q][key] wave-private rows, chunk-swizzled
    __shared__ bf16 Ks[2][64 * 64];  // [key][d] gld_lds dbuf, addr-swizzled
    __shared__ bf16 Vt[2][64 * 64];  // [d][key] gld_lds dbuf, addr-swizzled

    const int h = blockIdx.y;
    const int idx = PARTS_PER_HEAD - 1 - (int)blockIdx.x;   // heavy chunks first
    int g = 0;
    while (2 * (g + 1) * (g + 2) <= idx) ++g;
    const int rem = idx - 2 * g * (g + 1);
    const int qb = 4 * g + rem / (g + 1);
    const int c  = rem % (g + 1);
    const int ntiles = 2 * qb + 2;
    const int jstart = c * 8;
    const int jend   = (jstart + 8 < ntiles) ? jstart + 8 : ntiles;  // exclusive

    const int tid = threadIdx.x, lane = tid & 63, wave = tid >> 6;
    const int quad = lane >> 4, l16 = lane & 15, l8 = l16 & 7;
    const int qrow0 = qb * 128;
    const int cb = h * 64;

    auto stageKV = [&](int j, int buf) {
#pragma unroll
        for (int i = 0; i < 2; ++i) {
            int ch = i * 256 + tid;
            int row = ch >> 3, kg = ch & 7;
            int kgd = kg ^ (row & 7);
            gld16(K + (size_t)(j * 64 + row) * DM + cb + kgd * 8, &Ks[buf][ch * 8]);
        }
#pragma unroll
        for (int i = 0; i < 2; ++i) {
            int ch = i * 256 + tid;
            int row = ch >> 3, kg = ch & 7;     // row = d, kg = key-group
            int kgd = kg ^ (row & 7);
            gld16(VpT + (size_t)(cb + row) * S_LEN + j * 64 + kgd * 8, &Vt[buf][ch * 8]);
        }
    };

    // Q fragments (A-layout == B-layout of Q^T element-wise): wave-private rows
    bf16x8 qreg[2][2];
#pragma unroll
    for (int mt = 0; mt < 2; ++mt)
#pragma unroll
        for (int ks = 0; ks < 2; ++ks)
            qreg[mt][ks] = *(const bf16x8*)&Q[(size_t)(qrow0 + wave * 32 + mt * 16 + l16) * DM
                                             + cb + ks * 32 + quad * 8];

    stageKV(jstart, 0);
    __syncthreads();

    floatx4 o[2][4] = {};
    float lsum[2] = {0.f, 0.f};
    const int prowbase = (wave * 32 + l16) * 64;           // + mt*16*64
    const int psub = (quad & 1) * 4;
    const int c16base = (quad >> 1);

    for (int j = jstart; j < jend; ++j) {
        const int cur = (j - jstart) & 1;
        if (j + 1 < jend) stageKV(j + 1, cur ^ 1);   // async, overlaps compute

        // S^T = K @ Q^T   (lane: k = ct*16 + quad*4 + r, q = subtile + l16)
        floatx4 st[2][4] = {};
#pragma unroll
        for (int ks = 0; ks < 2; ++ks) {
            bf16x8 kfr[4];
#pragma unroll
            for (int ct = 0; ct < 4; ++ct)
                kfr[ct] = *(const bf16x8*)&Ks[cur][(ct * 16 + l16) * 64 + (((ks * 4 + quad) ^ l8) << 3)];
#pragma unroll
            for (int mt = 0; mt < 2; ++mt)
#pragma unroll
                for (int ct = 0; ct < 4; ++ct)
                    st[mt][ct] = MFMA16(kfr[ct], qreg[mt][ks], st[mt][ct]);
        }

        // softmax: p = exp2(st) (Q prescaled); pack 4 consecutive-k -> b64
#pragma unroll
        for (int mt = 0; mt < 2; ++mt) {
            const int qs0 = qrow0 + wave * 32 + mt * 16;
            const int pb = prowbase + mt * 16 * 64;
            float lp = 0.f;
            if ((j * 64 + 63) <= qs0) {          // interior tile: no mask ops
#pragma unroll
                for (int ct = 0; ct < 4; ++ct) {
                    bf16x4 pk;
#pragma unroll
                    for (int r = 0; r < 4; ++r) {
                        float p = __builtin_amdgcn_exp2f(st[mt][ct][r]);
                        lp += p; pk[r] = (bf16)p;
                    }
                    *(bf16x4*)&Ps[pb + ((((ct * 2 + c16base) ^ l8) << 3) + psub)] = pk;
                }
            } else {                              // diagonal tile: mask k > q
                const int qg = qs0 + l16;
#pragma unroll
                for (int ct = 0; ct < 4; ++ct) {
                    const int kg0 = j * 64 + ct * 16 + quad * 4;
                    bf16x4 pk;
#pragma unroll
                    for (int r = 0; r < 4; ++r) {
                        float p = (kg0 + r > qg) ? 0.f
                                  : __builtin_amdgcn_exp2f(st[mt][ct][r]);
                        lp += p; pk[r] = (bf16)p;
                    }
                    *(bf16x4*)&Ps[pb + ((((ct * 2 + c16base) ^ l8) << 3) + psub)] = pk;
                }
            }
            lsum[mt] += lp;
        }
        // Ps rows wave-private: no barrier

        // O += P @ V   (A = Ps b128 swizzled, B = Vt)
#pragma unroll
        for (int ks = 0; ks < 2; ++ks) {
            bf16x8 bfr[4], afr[2];
#pragma unroll
            for (int ct = 0; ct < 4; ++ct)
                bfr[ct] = *(const bf16x8*)&Vt[cur][(ct * 16 + l16) * 64 + (((ks * 4 + quad) ^ l8) << 3)];
#pragma unroll
            for (int mt = 0; mt < 2; ++mt)
                afr[mt] = *(const bf16x8*)&Ps[(wave * 32 + mt * 16 + l16) * 64 + (((ks * 4 + quad) ^ l8) << 3)];
#pragma unroll
            for (int mt = 0; mt < 2; ++mt)
#pragma unroll
                for (int ct = 0; ct < 4; ++ct)
                    o[mt][ct] = MFMA16(afr[mt], bfr[ct], o[mt][ct]);
        }

        __syncthreads();   // all waves done with cur; drains prefetch into nxt
    }

    // epilogue: bf16 unnormalized partial + per-row fp32 l
    bf16* Op = Opart + (size_t)(h * PARTS_PER_HEAD + idx) * 128 * 64;
    float* Lp = Lpart + (size_t)(h * PARTS_PER_HEAD + idx) * 128;
#pragma unroll
    for (int mt = 0; mt < 2; ++mt) {
        float l = lsum[mt];
        l += __shfl_xor(l, 16);
        l += __shfl_xor(l, 32);                  // full l for q = subtile + l16
        if (lane < 16) Lp[wave * 32 + mt * 16 + l16] = l;
#pragma unroll
        for (int r = 0; r < 4; ++r) {
            const int rl = wave * 32 + mt * 16 + quad * 4 + r;
#pragma unroll
            for (int ct = 0; ct < 4; ++ct)
                Op[rl * 64 + ct * 16 + l16] = (bf16)o[mt][ct][r];
        }
    }
}

// ---------------------------------------------------------------------------
// combine: X = (sum of bf16 partial O) / (sum of partial l), bf16 out
// ---------------------------------------------------------------------------
__global__ __launch_bounds__(256) void attn_combine_kernel(
    const bf16* __restrict__ Opart, const float* __restrict__ Lpart,
    bf16* __restrict__ X)
{
    const int qb = blockIdx.x, h = blockIdx.y;
    const int g = qb >> 2;
    const int nc = g + 1;
    const int base = 2 * g * (g + 1) + (qb & 3) * (g + 1);
    const bf16* Op0 = Opart + (size_t)(h * PARTS_PER_HEAD + base) * 128 * 64;
    const float* Lp0 = Lpart + (size_t)(h * PARTS_PER_HEAD + base) * 128;

    for (int e = threadIdx.x * 4; e < 128 * 64; e += 1024) {
        const int row = e >> 6, col = e & 63;
        float4 acc = {0.f, 0.f, 0.f, 0.f};
        float l = 0.f;
        for (int p = 0; p < nc; ++p) {
            bf16x4 w = *(const bf16x4*)&Op0[p * 128 * 64 + e];
            acc.x += (float)w[0]; acc.y += (float)w[1];
            acc.z += (float)w[2]; acc.w += (float)w[3];
            l += Lp0[p * 128 + row];
        }
        const float rl = 1.0f / l;
        bf16x4 ov;
        ov[0] = (bf16)(acc.x * rl); ov[1] = (bf16)(acc.y * rl);
        ov[2] = (bf16)(acc.z * rl); ov[3] = (bf16)(acc.w * rl);
        *(bf16x4*)&X[(size_t)(qb * 128 + row) * DM + h * 64 + col] = ov;
    }
}

// ---------------------------------------------------------------------------
extern "C" void kernel_launch(void* const* d_in, const int* in_sizes, int n_in,
                              void* d_out, int out_size, void* d_ws, size_t ws_size,
                              hipStream_t stream)
{
    const float* q  = (const float*)d_in[0];
    const float* k  = (const float*)d_in[1];
    const float* v  = (const float*)d_in[2];
    // d_in[3] = causal mask, handled analytically
    const float* Wq = (const float*)d_in[4];
    const float* bq = (const float*)d_in[5];
    const float* Wk = (const float*)d_in[6];
    const float* bk = (const float*)d_in[7];
    const float* Wv = (const float*)d_in[8];
    const float* bv = (const float*)d_in[9];
    const float* Wo = (const float*)d_in[10];
    const float* bo = (const float*)d_in[11];

    const size_t NE = (size_t)S_LEN * DM;     // 3,145,728 elems
    bf16* base = (bf16*)d_ws;
    // persistent:
    bf16* Qp = base;                          // reused as Xb after attn
    bf16* Kp = base + NE;
    bf16* Vp = base + 2 * NE;
    bf16* Wt = base + 3 * NE;                 // 4 transposed bf16 weights
    bf16 *Wqt = Wt, *Wkt = Wt + W_ELEMS, *Wvt = Wt + 2 * W_ELEMS, *Wot = Wt + 3 * W_ELEMS;
    bf16* VpT = Wt + 4 * W_ELEMS;             // [768][4096] transposed V proj
    // scratch: Qc/Kc/Vc (prep->gemmQKV) OVERLAID by Opart/Lpart (attn->combine)
    bf16* scratch = VpT + NE;
    bf16* Qc = scratch;
    bf16* Kc = scratch + NE;
    bf16* Vc = scratch + 2 * NE;
    bf16* Opart = scratch;                    // 12*144*128*64 bf16 = 28.3 MB
    float* Lpart = (float*)(Opart + (size_t)NH * PARTS_PER_HEAD * 128 * 64);
    bf16* Xb = Qp;                            // Qp dead after attn

    prep_kernel<<<dim3(3072, 4), 256, 0, stream>>>(
        q, k, v, Wq, Wk, Wv, Wo, Qc, Kc, Vc, Wqt, Wkt, Wvt, Wot, (int)NE);
    gemm128_kernel<false><<<dim3(32, 6, 3), 256, 0, stream>>>(
        Qc, Kc, Vc, Wqt, Wkt, Wvt, bq, bk, bv, Qp, Kp, Vp, S_LEN, DM, DM, CE);
    vtrans_kernel<<<dim3(64, 12), 256, 0, stream>>>(Vp, VpT);
    attn_kernel<<<dim3(PARTS_PER_HEAD, NH), 256, 0, stream>>>(Qp, Kp, VpT, Opart, Lpart);
    attn_combine_kernel<<<dim3(32, NH), 256, 0, stream>>>(Opart, Lpart, Xb);
    gemm128_kernel<true><<<dim3(32, 6, 1), 256, 0, stream>>>(
        Xb, Xb, Xb, Wot, Wot, Wot, bo, bo, bo, d_out, d_out, d_out, S_LEN, DM, DM, 1.0f);
}

// Round 8
// 257.549 us; speedup vs baseline: 1.0737x; 1.0118x over previous
//
#include <hip/hip_runtime.h>

typedef __bf16 bf16;
typedef __bf16 bf16x4 __attribute__((ext_vector_type(4)));
typedef __bf16 bf16x8 __attribute__((ext_vector_type(8)));
typedef float  floatx4 __attribute__((ext_vector_type(4)));

#define MFMA16(a,b,c) __builtin_amdgcn_mfma_f32_16x16x32_bf16((a),(b),(c),0,0,0)

static constexpr int S_LEN = 4096;
static constexpr int DM = 768;
static constexpr int NH = 12;
static constexpr int W_ELEMS = 768 * 768;
static constexpr int PARTS_PER_HEAD = 144;  // sum over qb=0..31 of ceil((qb+1)/4)
static constexpr float CE = 0.18033688011112042f;  // log2(e)/sqrt(64), folded into Q proj

__device__ __forceinline__ void gld16(const bf16* g, bf16* l) {
    __builtin_amdgcn_global_load_lds(
        (const __attribute__((address_space(1))) void*)g,
        (__attribute__((address_space(3))) void*)l, 16, 0, 0);
}

// ---------------------------------------------------------------------------
// prep: y<3 -> cast q/k/v fp32->bf16; y==3 -> cast+transpose 4 weight mats
// ---------------------------------------------------------------------------
__global__ __launch_bounds__(256) void prep_kernel(
    const float* __restrict__ q, const float* __restrict__ k, const float* __restrict__ v,
    const float* __restrict__ W0, const float* __restrict__ W1,
    const float* __restrict__ W2, const float* __restrict__ W3,
    bf16* Qc, bf16* Kc, bf16* Vc,
    bf16* T0, bf16* T1, bf16* T2, bf16* T3, int n)
{
    const int y = blockIdx.y;
    const int tid = threadIdx.x;
    if (y < 3) {
        const float* src = y == 0 ? q : (y == 1 ? k : v);
        bf16* dst = y == 0 ? Qc : (y == 1 ? Kc : Vc);
        int i = (blockIdx.x * 256 + tid) * 4;
        if (i < n) {
            float4 w = *(const float4*)&src[i];
            bf16x4 o; o[0] = (bf16)w.x; o[1] = (bf16)w.y; o[2] = (bf16)w.z; o[3] = (bf16)w.w;
            *(bf16x4*)&dst[i] = o;
        }
        return;
    }
    int x = blockIdx.x;
    if (x >= 576) return;
    const int mat = x / 144, t = x % 144;
    const float* W = mat == 0 ? W0 : (mat == 1 ? W1 : (mat == 2 ? W2 : W3));
    bf16* T = mat == 0 ? T0 : (mat == 1 ? T1 : (mat == 2 ? T2 : T3));
    const int k0 = (t / 12) * 64, n0 = (t % 12) * 64;
    __shared__ float Tl[64][65];
#pragma unroll
    for (int i = 0; i < 4; ++i) {
        int idx = i * 256 + tid;
        int r = idx >> 4, c4 = idx & 15;
        float4 w = *(const float4*)&W[(k0 + r) * 768 + n0 + c4 * 4];
        Tl[c4 * 4 + 0][r] = w.x; Tl[c4 * 4 + 1][r] = w.y;
        Tl[c4 * 4 + 2][r] = w.z; Tl[c4 * 4 + 3][r] = w.w;
    }
    __syncthreads();
#pragma unroll
    for (int i = 0; i < 4; ++i) {
        int idx = i * 256 + tid;
        int c = idx >> 4, r4 = idx & 15;
        bf16x4 o;
        o[0] = (bf16)Tl[c][r4 * 4 + 0]; o[1] = (bf16)Tl[c][r4 * 4 + 1];
        o[2] = (bf16)Tl[c][r4 * 4 + 2]; o[3] = (bf16)Tl[c][r4 * 4 + 3];
        *(bf16x4*)&T[(n0 + c) * 768 + k0 + r4 * 4] = o;
    }
}

// ---------------------------------------------------------------------------
// GEMM: C[M,N] = (A[M,K] @ Bt[N,K]^T + bias) * scale(z).
// 128m x 64n tile, BK=64, pipelined dbuf + gld_lds(16B), addr-side swizzle.
// 48 KB LDS -> 3 blocks/CU. Grid is (N/64, M/128, z): n FASTEST so the 12
// n-blocks sharing one A-strip run back-to-back (L2 A-broadcast, B resident).
// VT_Z2: z==2 writes C transposed (bf16) to O2 = VpT[768][4096] (fuses vtrans).
// ---------------------------------------------------------------------------
template <bool OUT_F32, bool VT_Z2>
__global__ __launch_bounds__(256) void gemm_kernel(
    const bf16* __restrict__ A0, const bf16* __restrict__ A1, const bf16* __restrict__ A2,
    const bf16* __restrict__ B0, const bf16* __restrict__ B1, const bf16* __restrict__ B2,
    const float* __restrict__ c0, const float* __restrict__ c1, const float* __restrict__ c2,
    void* O0, void* O1, void* O2, int M, int N, int K, float qscale)
{
    const int z = blockIdx.z;
    const bf16* A = z == 0 ? A0 : (z == 1 ? A1 : A2);
    const bf16* B = z == 0 ? B0 : (z == 1 ? B1 : B2);
    const float* bias = z == 0 ? c0 : (z == 1 ? c1 : c2);
    void* C = z == 0 ? O0 : (z == 1 ? O1 : O2);
    const float osc = (z == 0) ? qscale : 1.0f;

    __shared__ bf16 As[2][128 * 64];   // 32 KB
    __shared__ bf16 Bs[2][64 * 64];    // 16 KB
    const int tid = threadIdx.x, lane = tid & 63, wave = tid >> 6;
    const int quad = lane >> 4, l16 = lane & 15, l8 = l16 & 7;
    const int rw = wave >> 1, cw = wave & 1;     // wave: 64m x 32n subtile
    const int n0 = blockIdx.x * 64, m0 = blockIdx.y * 128;

    floatx4 acc[4][2] = {};

    auto stage = [&](int kt, int buf) {
#pragma unroll
        for (int i = 0; i < 4; ++i) {
            int ch = i * 256 + tid;                 // 1024 chunks of 16 B
            int m = ch >> 3, kg = ch & 7;
            int kgd = kg ^ (m & 7);
            gld16(A + (size_t)(m0 + m) * K + kt * 64 + kgd * 8, &As[buf][ch * 8]);
        }
#pragma unroll
        for (int i = 0; i < 2; ++i) {
            int ch = i * 256 + tid;                 // 512 chunks
            int n = ch >> 3, kg = ch & 7;
            int kgd = kg ^ (n & 7);
            gld16(B + (size_t)(n0 + n) * K + kt * 64 + kgd * 8, &Bs[buf][ch * 8]);
        }
    };

    const int NT = K >> 6;
    stage(0, 0);
    __syncthreads();

    for (int kt = 0; kt < NT; ++kt) {
        const int cur = kt & 1;
        if (kt + 1 < NT) stage(kt + 1, cur ^ 1);    // async prefetch
#pragma unroll
        for (int ks = 0; ks < 2; ++ks) {
            bf16x8 a[4], b[2];
#pragma unroll
            for (int mt = 0; mt < 4; ++mt)
                a[mt] = *(const bf16x8*)&As[cur][(rw * 64 + mt * 16 + l16) * 64 + (((ks * 4 + quad) ^ l8) << 3)];
#pragma unroll
            for (int nt = 0; nt < 2; ++nt)
                b[nt] = *(const bf16x8*)&Bs[cur][(cw * 32 + nt * 16 + l16) * 64 + (((ks * 4 + quad) ^ l8) << 3)];
#pragma unroll
            for (int mt = 0; mt < 4; ++mt)
#pragma unroll
                for (int nt = 0; nt < 2; ++nt)
                    acc[mt][nt] = MFMA16(a[mt], b[nt], acc[mt][nt]);
        }
        __syncthreads();
    }

    if (VT_Z2 && z == 2) {
        // transposed store: VpT[col][row], 4 consecutive rows packed as b64
#pragma unroll
        for (int mt = 0; mt < 4; ++mt) {
            int row = m0 + rw * 64 + mt * 16 + quad * 4;
#pragma unroll
            for (int nt = 0; nt < 2; ++nt) {
                int col = n0 + cw * 32 + nt * 16 + l16;
                float bv = bias[col];
                bf16x4 pk;
#pragma unroll
                for (int r = 0; r < 4; ++r) pk[r] = (bf16)(acc[mt][nt][r] + bv);
                *(bf16x4*)&((bf16*)C)[(size_t)col * S_LEN + row] = pk;
            }
        }
        return;
    }
#pragma unroll
    for (int mt = 0; mt < 4; ++mt) {
        int row = m0 + rw * 64 + mt * 16 + quad * 4;
#pragma unroll
        for (int nt = 0; nt < 2; ++nt) {
            int col = n0 + cw * 32 + nt * 16 + l16;
            float bv = bias[col];
#pragma unroll
            for (int r = 0; r < 4; ++r) {
                float v = (acc[mt][nt][r] + bv) * osc;
                if (OUT_F32) ((float*)C)[(size_t)(row + r) * N + col] = v;
                else         ((bf16*)C)[(size_t)(row + r) * N + col] = (bf16)v;
            }
        }
    }
}

// ---------------------------------------------------------------------------
// Split-K causal flash attention, S^T formulation, uniform chunks of 8 tiles.
// K AND V^T staged via async gld_lds double-buffer; one barrier per iter.
// bf16 partials. (frozen since R7)
// ---------------------------------------------------------------------------
__global__ __launch_bounds__(256) void attn_kernel(
    const bf16* __restrict__ Q, const bf16* __restrict__ K,
    const bf16* __restrict__ VpT, bf16* __restrict__ Opart,
    float* __restrict__ Lpart)
{
    __shared__ bf16 Ps[128 * 64];    // [q][key] wave-private rows, chunk-swizzled
    __shared__ bf16 Ks[2][64 * 64];  // [key][d] gld_lds dbuf, addr-swizzled
    __shared__ bf16 Vt[2][64 * 64];  // [d][key] gld_lds dbuf, addr-swizzled

    const int h = blockIdx.y;
    const int idx = PARTS_PER_HEAD - 1 - (int)blockIdx.x;   // heavy chunks first
    int g = 0;
    while (2 * (g + 1) * (g + 2) <= idx) ++g;
    const int rem = idx - 2 * g * (g + 1);
    const int qb = 4 * g + rem / (g + 1);
    const int c  = rem % (g + 1);
    const int ntiles = 2 * qb + 2;
    const int jstart = c * 8;
    const int jend   = (jstart + 8 < ntiles) ? jstart + 8 : ntiles;  // exclusive

    const int tid = threadIdx.x, lane = tid & 63, wave = tid >> 6;
    const int quad = lane >> 4, l16 = lane & 15, l8 = l16 & 7;
    const int qrow0 = qb * 128;
    const int cb = h * 64;

    auto stageKV = [&](int j, int buf) {
#pragma unroll
        for (int i = 0; i < 2; ++i) {
            int ch = i * 256 + tid;
            int row = ch >> 3, kg = ch & 7;
            int kgd = kg ^ (row & 7);
            gld16(K + (size_t)(j * 64 + row) * DM + cb + kgd * 8, &Ks[buf][ch * 8]);
        }
#pragma unroll
        for (int i = 0; i < 2; ++i) {
            int ch = i * 256 + tid;
            int row = ch >> 3, kg = ch & 7;     // row = d, kg = key-group
            int kgd = kg ^ (row & 7);
            gld16(VpT + (size_t)(cb + row) * S_LEN + j * 64 + kgd * 8, &Vt[buf][ch * 8]);
        }
    };

    // Q fragments (A-layout == B-layout of Q^T element-wise): wave-private rows
    bf16x8 qreg[2][2];
#pragma unroll
    for (int mt = 0; mt < 2; ++mt)
#pragma unroll
        for (int ks = 0; ks < 2; ++ks)
            qreg[mt][ks] = *(const bf16x8*)&Q[(size_t)(qrow0 + wave * 32 + mt * 16 + l16) * DM
                                             + cb + ks * 32 + quad * 8];

    stageKV(jstart, 0);
    __syncthreads();

    floatx4 o[2][4] = {};
    float lsum[2] = {0.f, 0.f};
    const int prowbase = (wave * 32 + l16) * 64;           // + mt*16*64
    const int psub = (quad & 1) * 4;
    const int c16base = (quad >> 1);

    for (int j = jstart; j < jend; ++j) {
        const int cur = (j - jstart) & 1;
        if (j + 1 < jend) stageKV(j + 1, cur ^ 1);   // async, overlaps compute

        // S^T = K @ Q^T   (lane: k = ct*16 + quad*4 + r, q = subtile + l16)
        floatx4 st[2][4] = {};
#pragma unroll
        for (int ks = 0; ks < 2; ++ks) {
            bf16x8 kfr[4];
#pragma unroll
            for (int ct = 0; ct < 4; ++ct)
                kfr[ct] = *(const bf16x8*)&Ks[cur][(ct * 16 + l16) * 64 + (((ks * 4 + quad) ^ l8) << 3)];
#pragma unroll
            for (int mt = 0; mt < 2; ++mt)
#pragma unroll
                for (int ct = 0; ct < 4; ++ct)
                    st[mt][ct] = MFMA16(kfr[ct], qreg[mt][ks], st[mt][ct]);
        }

        // softmax: p = exp2(st) (Q prescaled); pack 4 consecutive-k -> b64
#pragma unroll
        for (int mt = 0; mt < 2; ++mt) {
            const int qs0 = qrow0 + wave * 32 + mt * 16;
            const int pb = prowbase + mt * 16 * 64;
            float lp = 0.f;
            if ((j * 64 + 63) <= qs0) {          // interior tile: no mask ops
#pragma unroll
                for (int ct = 0; ct < 4; ++ct) {
                    bf16x4 pk;
#pragma unroll
                    for (int r = 0; r < 4; ++r) {
                        float p = __builtin_amdgcn_exp2f(st[mt][ct][r]);
                        lp += p; pk[r] = (bf16)p;
                    }
                    *(bf16x4*)&Ps[pb + ((((ct * 2 + c16base) ^ l8) << 3) + psub)] = pk;
                }
            } else {                              // diagonal tile: mask k > q
                const int qg = qs0 + l16;
#pragma unroll
                for (int ct = 0; ct < 4; ++ct) {
                    const int kg0 = j * 64 + ct * 16 + quad * 4;
                    bf16x4 pk;
#pragma unroll
                    for (int r = 0; r < 4; ++r) {
                        float p = (kg0 + r > qg) ? 0.f
                                  : __builtin_amdgcn_exp2f(st[mt][ct][r]);
                        lp += p; pk[r] = (bf16)p;
                    }
                    *(bf16x4*)&Ps[pb + ((((ct * 2 + c16base) ^ l8) << 3) + psub)] = pk;
                }
            }
            lsum[mt] += lp;
        }
        // Ps rows wave-private: no barrier

        // O += P @ V   (A = Ps b128 swizzled, B = Vt)
#pragma unroll
        for (int ks = 0; ks < 2; ++ks) {
            bf16x8 bfr[4], afr[2];
#pragma unroll
            for (int ct = 0; ct < 4; ++ct)
                bfr[ct] = *(const bf16x8*)&Vt[cur][(ct * 16 + l16) * 64 + (((ks * 4 + quad) ^ l8) << 3)];
#pragma unroll
            for (int mt = 0; mt < 2; ++mt)
                afr[mt] = *(const bf16x8*)&Ps[(wave * 32 + mt * 16 + l16) * 64 + (((ks * 4 + quad) ^ l8) << 3)];
#pragma unroll
            for (int mt = 0; mt < 2; ++mt)
#pragma unroll
                for (int ct = 0; ct < 4; ++ct)
                    o[mt][ct] = MFMA16(afr[mt], bfr[ct], o[mt][ct]);
        }

        __syncthreads();   // all waves done with cur; drains prefetch into nxt
    }

    // epilogue: bf16 unnormalized partial + per-row fp32 l
    bf16* Op = Opart + (size_t)(h * PARTS_PER_HEAD + idx) * 128 * 64;
    float* Lp = Lpart + (size_t)(h * PARTS_PER_HEAD + idx) * 128;
#pragma unroll
    for (int mt = 0; mt < 2; ++mt) {
        float l = lsum[mt];
        l += __shfl_xor(l, 16);
        l += __shfl_xor(l, 32);                  // full l for q = subtile + l16
        if (lane < 16) Lp[wave * 32 + mt * 16 + l16] = l;
#pragma unroll
        for (int r = 0; r < 4; ++r) {
            const int rl = wave * 32 + mt * 16 + quad * 4 + r;
#pragma unroll
            for (int ct = 0; ct < 4; ++ct)
                Op[rl * 64 + ct * 16 + l16] = (bf16)o[mt][ct][r];
        }
    }
}

// ---------------------------------------------------------------------------
// combine: X = (sum of bf16 partial O) / (sum of partial l), bf16 out
// ---------------------------------------------------------------------------
__global__ __launch_bounds__(256) void attn_combine_kernel(
    const bf16* __restrict__ Opart, const float* __restrict__ Lpart,
    bf16* __restrict__ X)
{
    const int qb = blockIdx.x, h = blockIdx.y;
    const int g = qb >> 2;
    const int nc = g + 1;
    const int base = 2 * g * (g + 1) + (qb & 3) * (g + 1);
    const bf16* Op0 = Opart + (size_t)(h * PARTS_PER_HEAD + base) * 128 * 64;
    const float* Lp0 = Lpart + (size_t)(h * PARTS_PER_HEAD + base) * 128;

    for (int e = threadIdx.x * 4; e < 128 * 64; e += 1024) {
        const int row = e >> 6, col = e & 63;
        float4 acc = {0.f, 0.f, 0.f, 0.f};
        float l = 0.f;
        for (int p = 0; p < nc; ++p) {
            bf16x4 w = *(const bf16x4*)&Op0[p * 128 * 64 + e];
            acc.x += (float)w[0]; acc.y += (float)w[1];
            acc.z += (float)w[2]; acc.w += (float)w[3];
            l += Lp0[p * 128 + row];
        }
        const float rl = 1.0f / l;
        bf16x4 ov;
        ov[0] = (bf16)(acc.x * rl); ov[1] = (bf16)(acc.y * rl);
        ov[2] = (bf16)(acc.z * rl); ov[3] = (bf16)(acc.w * rl);
        *(bf16x4*)&X[(size_t)(qb * 128 + row) * DM + h * 64 + col] = ov;
    }
}

// ---------------------------------------------------------------------------
extern "C" void kernel_launch(void* const* d_in, const int* in_sizes, int n_in,
                              void* d_out, int out_size, void* d_ws, size_t ws_size,
                              hipStream_t stream)
{
    const float* q  = (const float*)d_in[0];
    const float* k  = (const float*)d_in[1];
    const float* v  = (const float*)d_in[2];
    // d_in[3] = causal mask, handled analytically
    const float* Wq = (const float*)d_in[4];
    const float* bq = (const float*)d_in[5];
    const float* Wk = (const float*)d_in[6];
    const float* bk = (const float*)d_in[7];
    const float* Wv = (const float*)d_in[8];
    const float* bv = (const float*)d_in[9];
    const float* Wo = (const float*)d_in[10];
    const float* bo = (const float*)d_in[11];

    const size_t NE = (size_t)S_LEN * DM;     // 3,145,728 elems
    bf16* base = (bf16*)d_ws;
    // persistent:
    bf16* Qp  = base;                         // reused as Xb after attn
    bf16* Kp  = base + NE;
    bf16* VpT = base + 2 * NE;                // [768][4096] V proj, transposed
    bf16* Wt  = base + 3 * NE;                // 4 transposed bf16 weights
    bf16 *Wqt = Wt, *Wkt = Wt + W_ELEMS, *Wvt = Wt + 2 * W_ELEMS, *Wot = Wt + 3 * W_ELEMS;
    // scratch: Qc/Kc/Vc (prep->gemmQKV) OVERLAID by Opart/Lpart (attn->combine)
    bf16* scratch = Wt + 4 * W_ELEMS;
    bf16* Qc = scratch;
    bf16* Kc = scratch + NE;
    bf16* Vc = scratch + 2 * NE;
    bf16* Opart = scratch;                    // 12*144*128*64 bf16 = 28.3 MB
    float* Lpart = (float*)(Opart + (size_t)NH * PARTS_PER_HEAD * 128 * 64);
    bf16* Xb = Qp;                            // Qp dead after attn

    prep_kernel<<<dim3(3072, 4), 256, 0, stream>>>(
        q, k, v, Wq, Wk, Wv, Wo, Qc, Kc, Vc, Wqt, Wkt, Wvt, Wot, (int)NE);
    // n-fastest grid: (N/64, M/128, z); z==2 writes VpT transposed
    gemm_kernel<false, true><<<dim3(12, 32, 3), 256, 0, stream>>>(
        Qc, Kc, Vc, Wqt, Wkt, Wvt, bq, bk, bv, Qp, Kp, VpT, S_LEN, DM, DM, CE);
    attn_kernel<<<dim3(PARTS_PER_HEAD, NH), 256, 0, stream>>>(Qp, Kp, VpT, Opart, Lpart);
    attn_combine_kernel<<<dim3(32, NH), 256, 0, stream>>>(Opart, Lpart, Xb);
    gemm_kernel<true, false><<<dim3(12, 32, 1), 256, 0, stream>>>(
        Xb, Xb, Xb, Wot, Wot, Wot, bo, bo, bo, d_out, d_out, d_out, S_LEN, DM, DM, 1.0f);
}

// Round 9
// 257.515 us; speedup vs baseline: 1.0738x; 1.0001x over previous
//
#include <hip/hip_runtime.h>

typedef __bf16 bf16;
typedef __bf16 bf16x4 __attribute__((ext_vector_type(4)));
typedef __bf16 bf16x8 __attribute__((ext_vector_type(8)));
typedef float  floatx4 __attribute__((ext_vector_type(4)));

#define MFMA16(a,b,c) __builtin_amdgcn_mfma_f32_16x16x32_bf16((a),(b),(c),0,0,0)

static constexpr int S_LEN = 4096;
static constexpr int DM = 768;
static constexpr int NH = 12;
static constexpr int W_ELEMS = 768 * 768;
static constexpr int PARTS_PER_HEAD = 144;  // sum over qb=0..31 of ceil((qb+1)/4)
static constexpr float CE = 0.18033688011112042f;  // log2(e)/sqrt(64), folded into Q proj

__device__ __forceinline__ void gld16(const bf16* g, bf16* l) {
    __builtin_amdgcn_global_load_lds(
        (const __attribute__((address_space(1))) void*)g,
        (__attribute__((address_space(3))) void*)l, 16, 0, 0);
}

// ---------------------------------------------------------------------------
// prep: y<3 -> cast q/k/v fp32->bf16; y==3 -> cast+transpose 4 weight mats
// ---------------------------------------------------------------------------
__global__ __launch_bounds__(256) void prep_kernel(
    const float* __restrict__ q, const float* __restrict__ k, const float* __restrict__ v,
    const float* __restrict__ W0, const float* __restrict__ W1,
    const float* __restrict__ W2, const float* __restrict__ W3,
    bf16* Qc, bf16* Kc, bf16* Vc,
    bf16* T0, bf16* T1, bf16* T2, bf16* T3, int n)
{
    const int y = blockIdx.y;
    const int tid = threadIdx.x;
    if (y < 3) {
        const float* src = y == 0 ? q : (y == 1 ? k : v);
        bf16* dst = y == 0 ? Qc : (y == 1 ? Kc : Vc);
        int i = (blockIdx.x * 256 + tid) * 4;
        if (i < n) {
            float4 w = *(const float4*)&src[i];
            bf16x4 o; o[0] = (bf16)w.x; o[1] = (bf16)w.y; o[2] = (bf16)w.z; o[3] = (bf16)w.w;
            *(bf16x4*)&dst[i] = o;
        }
        return;
    }
    int x = blockIdx.x;
    if (x >= 576) return;
    const int mat = x / 144, t = x % 144;
    const float* W = mat == 0 ? W0 : (mat == 1 ? W1 : (mat == 2 ? W2 : W3));
    bf16* T = mat == 0 ? T0 : (mat == 1 ? T1 : (mat == 2 ? T2 : T3));
    const int k0 = (t / 12) * 64, n0 = (t % 12) * 64;
    __shared__ float Tl[64][65];
#pragma unroll
    for (int i = 0; i < 4; ++i) {
        int idx = i * 256 + tid;
        int r = idx >> 4, c4 = idx & 15;
        float4 w = *(const float4*)&W[(k0 + r) * 768 + n0 + c4 * 4];
        Tl[c4 * 4 + 0][r] = w.x; Tl[c4 * 4 + 1][r] = w.y;
        Tl[c4 * 4 + 2][r] = w.z; Tl[c4 * 4 + 3][r] = w.w;
    }
    __syncthreads();
#pragma unroll
    for (int i = 0; i < 4; ++i) {
        int idx = i * 256 + tid;
        int c = idx >> 4, r4 = idx & 15;
        bf16x4 o;
        o[0] = (bf16)Tl[c][r4 * 4 + 0]; o[1] = (bf16)Tl[c][r4 * 4 + 1];
        o[2] = (bf16)Tl[c][r4 * 4 + 2]; o[3] = (bf16)Tl[c][r4 * 4 + 3];
        *(bf16x4*)&T[(n0 + c) * 768 + k0 + r4 * 4] = o;
    }
}

// ---------------------------------------------------------------------------
// GEMM: C[M,N] = (A[M,K] @ Bt[N,K]^T + bias) * scale(z).
// 128m x 64n tile, BK=64, pipelined dbuf + gld_lds(16B), addr-side swizzle.
// 48 KB LDS -> 3 blocks/CU. Grid (N/64, M/128, z), n fastest.
// VT_Z2: z==2 writes C transposed (bf16) to O2 = VpT[768][4096]. (frozen R8)
// ---------------------------------------------------------------------------
template <bool OUT_F32, bool VT_Z2>
__global__ __launch_bounds__(256) void gemm_kernel(
    const bf16* __restrict__ A0, const bf16* __restrict__ A1, const bf16* __restrict__ A2,
    const bf16* __restrict__ B0, const bf16* __restrict__ B1, const bf16* __restrict__ B2,
    const float* __restrict__ c0, const float* __restrict__ c1, const float* __restrict__ c2,
    void* O0, void* O1, void* O2, int M, int N, int K, float qscale)
{
    const int z = blockIdx.z;
    const bf16* A = z == 0 ? A0 : (z == 1 ? A1 : A2);
    const bf16* B = z == 0 ? B0 : (z == 1 ? B1 : B2);
    const float* bias = z == 0 ? c0 : (z == 1 ? c1 : c2);
    void* C = z == 0 ? O0 : (z == 1 ? O1 : O2);
    const float osc = (z == 0) ? qscale : 1.0f;

    __shared__ bf16 As[2][128 * 64];   // 32 KB
    __shared__ bf16 Bs[2][64 * 64];    // 16 KB
    const int tid = threadIdx.x, lane = tid & 63, wave = tid >> 6;
    const int quad = lane >> 4, l16 = lane & 15, l8 = l16 & 7;
    const int rw = wave >> 1, cw = wave & 1;     // wave: 64m x 32n subtile
    const int n0 = blockIdx.x * 64, m0 = blockIdx.y * 128;

    floatx4 acc[4][2] = {};

    auto stage = [&](int kt, int buf) {
#pragma unroll
        for (int i = 0; i < 4; ++i) {
            int ch = i * 256 + tid;
            int m = ch >> 3, kg = ch & 7;
            int kgd = kg ^ (m & 7);
            gld16(A + (size_t)(m0 + m) * K + kt * 64 + kgd * 8, &As[buf][ch * 8]);
        }
#pragma unroll
        for (int i = 0; i < 2; ++i) {
            int ch = i * 256 + tid;
            int n = ch >> 3, kg = ch & 7;
            int kgd = kg ^ (n & 7);
            gld16(B + (size_t)(n0 + n) * K + kt * 64 + kgd * 8, &Bs[buf][ch * 8]);
        }
    };

    const int NT = K >> 6;
    stage(0, 0);
    __syncthreads();

    for (int kt = 0; kt < NT; ++kt) {
        const int cur = kt & 1;
        if (kt + 1 < NT) stage(kt + 1, cur ^ 1);
#pragma unroll
        for (int ks = 0; ks < 2; ++ks) {
            bf16x8 a[4], b[2];
#pragma unroll
            for (int mt = 0; mt < 4; ++mt)
                a[mt] = *(const bf16x8*)&As[cur][(rw * 64 + mt * 16 + l16) * 64 + (((ks * 4 + quad) ^ l8) << 3)];
#pragma unroll
            for (int nt = 0; nt < 2; ++nt)
                b[nt] = *(const bf16x8*)&Bs[cur][(cw * 32 + nt * 16 + l16) * 64 + (((ks * 4 + quad) ^ l8) << 3)];
#pragma unroll
            for (int mt = 0; mt < 4; ++mt)
#pragma unroll
                for (int nt = 0; nt < 2; ++nt)
                    acc[mt][nt] = MFMA16(a[mt], b[nt], acc[mt][nt]);
        }
        __syncthreads();
    }

    if (VT_Z2 && z == 2) {
#pragma unroll
        for (int mt = 0; mt < 4; ++mt) {
            int row = m0 + rw * 64 + mt * 16 + quad * 4;
#pragma unroll
            for (int nt = 0; nt < 2; ++nt) {
                int col = n0 + cw * 32 + nt * 16 + l16;
                float bv = bias[col];
                bf16x4 pk;
#pragma unroll
                for (int r = 0; r < 4; ++r) pk[r] = (bf16)(acc[mt][nt][r] + bv);
                *(bf16x4*)&((bf16*)C)[(size_t)col * S_LEN + row] = pk;
            }
        }
        return;
    }
#pragma unroll
    for (int mt = 0; mt < 4; ++mt) {
        int row = m0 + rw * 64 + mt * 16 + quad * 4;
#pragma unroll
        for (int nt = 0; nt < 2; ++nt) {
            int col = n0 + cw * 32 + nt * 16 + l16;
            float bv = bias[col];
#pragma unroll
            for (int r = 0; r < 4; ++r) {
                float v = (acc[mt][nt][r] + bv) * osc;
                if (OUT_F32) ((float*)C)[(size_t)(row + r) * N + col] = v;
                else         ((bf16*)C)[(size_t)(row + r) * N + col] = (bf16)v;
            }
        }
    }
}

// ---------------------------------------------------------------------------
// Split-K causal flash attention, S^T formulation, uniform chunks of 8 tiles.
// NEW (R9): l computed on the MFMA pipe as P @ ones (constant B fragment) --
// removes 32 VALU adds/iter + the epilogue cross-lane reduction. l is summed
// over the same bf16-rounded P that O uses (masked elems are 0 in Ps).
// ---------------------------------------------------------------------------
__global__ __launch_bounds__(256) void attn_kernel(
    const bf16* __restrict__ Q, const bf16* __restrict__ K,
    const bf16* __restrict__ VpT, bf16* __restrict__ Opart,
    float* __restrict__ Lpart)
{
    __shared__ bf16 Ps[128 * 64];    // [q][key] wave-private rows, chunk-swizzled
    __shared__ bf16 Ks[2][64 * 64];  // [key][d] gld_lds dbuf, addr-swizzled
    __shared__ bf16 Vt[2][64 * 64];  // [d][key] gld_lds dbuf, addr-swizzled

    const int h = blockIdx.y;
    const int idx = PARTS_PER_HEAD - 1 - (int)blockIdx.x;   // heavy chunks first
    int g = 0;
    while (2 * (g + 1) * (g + 2) <= idx) ++g;
    const int rem = idx - 2 * g * (g + 1);
    const int qb = 4 * g + rem / (g + 1);
    const int c  = rem % (g + 1);
    const int ntiles = 2 * qb + 2;
    const int jstart = c * 8;
    const int jend   = (jstart + 8 < ntiles) ? jstart + 8 : ntiles;  // exclusive

    const int tid = threadIdx.x, lane = tid & 63, wave = tid >> 6;
    const int quad = lane >> 4, l16 = lane & 15, l8 = l16 & 7;
    const int qrow0 = qb * 128;
    const int cb = h * 64;

    auto stageKV = [&](int j, int buf) {
#pragma unroll
        for (int i = 0; i < 2; ++i) {
            int ch = i * 256 + tid;
            int row = ch >> 3, kg = ch & 7;
            int kgd = kg ^ (row & 7);
            gld16(K + (size_t)(j * 64 + row) * DM + cb + kgd * 8, &Ks[buf][ch * 8]);
        }
#pragma unroll
        for (int i = 0; i < 2; ++i) {
            int ch = i * 256 + tid;
            int row = ch >> 3, kg = ch & 7;     // row = d, kg = key-group
            int kgd = kg ^ (row & 7);
            gld16(VpT + (size_t)(cb + row) * S_LEN + j * 64 + kgd * 8, &Vt[buf][ch * 8]);
        }
    };

    // Q fragments (A-layout == B-layout of Q^T element-wise): wave-private rows
    bf16x8 qreg[2][2];
#pragma unroll
    for (int mt = 0; mt < 2; ++mt)
#pragma unroll
        for (int ks = 0; ks < 2; ++ks)
            qreg[mt][ks] = *(const bf16x8*)&Q[(size_t)(qrow0 + wave * 32 + mt * 16 + l16) * DM
                                             + cb + ks * 32 + quad * 8];

    // constant all-ones B fragment for the l = P @ 1 MFMA
    bf16x8 ones;
#pragma unroll
    for (int u = 0; u < 8; ++u) ones[u] = (bf16)1.0f;

    stageKV(jstart, 0);
    __syncthreads();

    floatx4 o[2][4] = {};
    floatx4 o_l[2] = {};
    const int prowbase = (wave * 32 + l16) * 64;           // + mt*16*64
    const int psub = (quad & 1) * 4;
    const int c16base = (quad >> 1);

    for (int j = jstart; j < jend; ++j) {
        const int cur = (j - jstart) & 1;
        if (j + 1 < jend) stageKV(j + 1, cur ^ 1);   // async, overlaps compute

        // S^T = K @ Q^T   (lane: k = ct*16 + quad*4 + r, q = subtile + l16)
        floatx4 st[2][4] = {};
#pragma unroll
        for (int ks = 0; ks < 2; ++ks) {
            bf16x8 kfr[4];
#pragma unroll
            for (int ct = 0; ct < 4; ++ct)
                kfr[ct] = *(const bf16x8*)&Ks[cur][(ct * 16 + l16) * 64 + (((ks * 4 + quad) ^ l8) << 3)];
#pragma unroll
            for (int mt = 0; mt < 2; ++mt)
#pragma unroll
                for (int ct = 0; ct < 4; ++ct)
                    st[mt][ct] = MFMA16(kfr[ct], qreg[mt][ks], st[mt][ct]);
        }

        // softmax: p = exp2(st) (Q prescaled); pack 4 consecutive-k -> b64
#pragma unroll
        for (int mt = 0; mt < 2; ++mt) {
            const int qs0 = qrow0 + wave * 32 + mt * 16;
            const int pb = prowbase + mt * 16 * 64;
            if ((j * 64 + 63) <= qs0) {          // interior tile: no mask ops
#pragma unroll
                for (int ct = 0; ct < 4; ++ct) {
                    bf16x4 pk;
#pragma unroll
                    for (int r = 0; r < 4; ++r)
                        pk[r] = (bf16)__builtin_amdgcn_exp2f(st[mt][ct][r]);
                    *(bf16x4*)&Ps[pb + ((((ct * 2 + c16base) ^ l8) << 3) + psub)] = pk;
                }
            } else {                              // diagonal tile: mask k > q
                const int qg = qs0 + l16;
#pragma unroll
                for (int ct = 0; ct < 4; ++ct) {
                    const int kg0 = j * 64 + ct * 16 + quad * 4;
                    bf16x4 pk;
#pragma unroll
                    for (int r = 0; r < 4; ++r) {
                        float p = (kg0 + r > qg) ? 0.f
                                  : __builtin_amdgcn_exp2f(st[mt][ct][r]);
                        pk[r] = (bf16)p;
                    }
                    *(bf16x4*)&Ps[pb + ((((ct * 2 + c16base) ^ l8) << 3) + psub)] = pk;
                }
            }
        }
        // Ps rows wave-private: no barrier

        // O += P @ V, l += P @ 1   (A = Ps b128 swizzled, B = Vt / ones)
#pragma unroll
        for (int ks = 0; ks < 2; ++ks) {
            bf16x8 bfr[4], afr[2];
#pragma unroll
            for (int ct = 0; ct < 4; ++ct)
                bfr[ct] = *(const bf16x8*)&Vt[cur][(ct * 16 + l16) * 64 + (((ks * 4 + quad) ^ l8) << 3)];
#pragma unroll
            for (int mt = 0; mt < 2; ++mt)
                afr[mt] = *(const bf16x8*)&Ps[(wave * 32 + mt * 16 + l16) * 64 + (((ks * 4 + quad) ^ l8) << 3)];
#pragma unroll
            for (int mt = 0; mt < 2; ++mt) {
#pragma unroll
                for (int ct = 0; ct < 4; ++ct)
                    o[mt][ct] = MFMA16(afr[mt], bfr[ct], o[mt][ct]);
                o_l[mt] = MFMA16(afr[mt], ones, o_l[mt]);
            }
        }

        __syncthreads();   // all waves done with cur; drains prefetch into nxt
    }

    // epilogue: bf16 unnormalized partial + per-row fp32 l (C-layout, col-dup)
    bf16* Op = Opart + (size_t)(h * PARTS_PER_HEAD + idx) * 128 * 64;
    float* Lp = Lpart + (size_t)(h * PARTS_PER_HEAD + idx) * 128;
#pragma unroll
    for (int mt = 0; mt < 2; ++mt) {
#pragma unroll
        for (int r = 0; r < 4; ++r) {
            const int rl = wave * 32 + mt * 16 + quad * 4 + r;
            if (l16 == 0) Lp[rl] = o_l[mt][r];
#pragma unroll
            for (int ct = 0; ct < 4; ++ct)
                Op[rl * 64 + ct * 16 + l16] = (bf16)o[mt][ct][r];
        }
    }
}

// ---------------------------------------------------------------------------
// combine: X = (sum of bf16 partial O) / (sum of partial l), bf16 out
// ---------------------------------------------------------------------------
__global__ __launch_bounds__(256) void attn_combine_kernel(
    const bf16* __restrict__ Opart, const float* __restrict__ Lpart,
    bf16* __restrict__ X)
{
    const int qb = blockIdx.x, h = blockIdx.y;
    const int g = qb >> 2;
    const int nc = g + 1;
    const int base = 2 * g * (g + 1) + (qb & 3) * (g + 1);
    const bf16* Op0 = Opart + (size_t)(h * PARTS_PER_HEAD + base) * 128 * 64;
    const float* Lp0 = Lpart + (size_t)(h * PARTS_PER_HEAD + base) * 128;

    for (int e = threadIdx.x * 4; e < 128 * 64; e += 1024) {
        const int row = e >> 6, col = e & 63;
        float4 acc = {0.f, 0.f, 0.f, 0.f};
        float l = 0.f;
        for (int p = 0; p < nc; ++p) {
            bf16x4 w = *(const bf16x4*)&Op0[p * 128 * 64 + e];
            acc.x += (float)w[0]; acc.y += (float)w[1];
            acc.z += (float)w[2]; acc.w += (float)w[3];
            l += Lp0[p * 128 + row];
        }
        const float rl = 1.0f / l;
        bf16x4 ov;
        ov[0] = (bf16)(acc.x * rl); ov[1] = (bf16)(acc.y * rl);
        ov[2] = (bf16)(acc.z * rl); ov[3] = (bf16)(acc.w * rl);
        *(bf16x4*)&X[(size_t)(qb * 128 + row) * DM + h * 64 + col] = ov;
    }
}

// ---------------------------------------------------------------------------
extern "C" void kernel_launch(void* const* d_in, const int* in_sizes, int n_in,
                              void* d_out, int out_size, void* d_ws, size_t ws_size,
                              hipStream_t stream)
{
    const float* q  = (const float*)d_in[0];
    const float* k  = (const float*)d_in[1];
    const float* v  = (const float*)d_in[2];
    // d_in[3] = causal mask, handled analytically
    const float* Wq = (const float*)d_in[4];
    const float* bq = (const float*)d_in[5];
    const float* Wk = (const float*)d_in[6];
    const float* bk = (const float*)d_in[7];
    const float* Wv = (const float*)d_in[8];
    const float* bv = (const float*)d_in[9];
    const float* Wo = (const float*)d_in[10];
    const float* bo = (const float*)d_in[11];

    const size_t NE = (size_t)S_LEN * DM;     // 3,145,728 elems
    bf16* base = (bf16*)d_ws;
    // persistent:
    bf16* Qp  = base;                         // reused as Xb after attn
    bf16* Kp  = base + NE;
    bf16* VpT = base + 2 * NE;                // [768][4096] V proj, transposed
    bf16* Wt  = base + 3 * NE;                // 4 transposed bf16 weights
    bf16 *Wqt = Wt, *Wkt = Wt + W_ELEMS, *Wvt = Wt + 2 * W_ELEMS, *Wot = Wt + 3 * W_ELEMS;
    // scratch: Qc/Kc/Vc (prep->gemmQKV) OVERLAID by Opart/Lpart (attn->combine)
    bf16* scratch = Wt + 4 * W_ELEMS;
    bf16* Qc = scratch;
    bf16* Kc = scratch + NE;
    bf16* Vc = scratch + 2 * NE;
    bf16* Opart = scratch;                    // 12*144*128*64 bf16 = 28.3 MB
    float* Lpart = (float*)(Opart + (size_t)NH * PARTS_PER_HEAD * 128 * 64);
    bf16* Xb = Qp;                            // Qp dead after attn

    prep_kernel<<<dim3(3072, 4), 256, 0, stream>>>(
        q, k, v, Wq, Wk, Wv, Wo, Qc, Kc, Vc, Wqt, Wkt, Wvt, Wot, (int)NE);
    gemm_kernel<false, true><<<dim3(12, 32, 3), 256, 0, stream>>>(
        Qc, Kc, Vc, Wqt, Wkt, Wvt, bq, bk, bv, Qp, Kp, VpT, S_LEN, DM, DM, CE);
    attn_kernel<<<dim3(PARTS_PER_HEAD, NH), 256, 0, stream>>>(Qp, Kp, VpT, Opart, Lpart);
    attn_combine_kernel<<<dim3(32, NH), 256, 0, stream>>>(Opart, Lpart, Xb);
    gemm_kernel<true, false><<<dim3(12, 32, 1), 256, 0, stream>>>(
        Xb, Xb, Xb, Wot, Wot, Wot, bo, bo, bo, d_out, d_out, d_out, S_LEN, DM, DM, 1.0f);
}